// Round 6
// baseline (297.864 us; speedup 1.0000x reference)
//
#include <hip/hip_runtime.h>
#include <hip/hip_fp16.h>

// Problem constants: x (1,64,8,56,56), offset (1,648,8,56,56),
// weight (64,64,3,3,3), stride=1, pad=1, cpg=8.
namespace {
constexpr int D_ = 8, H_ = 56, W_ = 56;
constexpr int HW_ = H_ * W_;
constexpr int KV_ = 27;
constexpr int N_ = D_ * H_ * W_;    // 25088
constexpr int NT_ = 16;             // n-cols per tile (one MFMA n-dim)
constexpr int NTILES_ = N_ / NT_;   // 1568 = 8 * 196
}

typedef _Float16 f16x8 __attribute__((ext_vector_type(8)));
typedef float f32x4 __attribute__((ext_vector_type(4)));

union U4H { uint4 u; __half2 h[4]; f16x8 v; };

// prep: xt[g][n][8] f16  and  wt2[kv][of][ks][lane][8] f16
//   wt2[kv][of][ks][l][e] = w[o = of*16 + (l&15)][c = ks*32 + (l>>4)*8 + e]
__global__ __launch_bounds__(256) void prep_kernel(const float* __restrict__ x,
                                                   const float* __restrict__ w,
                                                   __half* __restrict__ xt,
                                                   __half* __restrict__ wt2) {
    const int b = blockIdx.x, tid = threadIdx.x;
    if (b < 784) {
        const int g = b / 98;
        const int n = (b % 98) * 256 + tid;
        U4H p;
#pragma unroll
        for (int cc = 0; cc < 4; ++cc) {
            float lo = x[(size_t)(g * 8 + 2 * cc) * N_ + n];
            float hi = x[(size_t)(g * 8 + 2 * cc + 1) * N_ + n];
            p.h[cc] = __floats2half2_rn(lo, hi);
        }
        *(uint4*)(xt + ((size_t)g * N_ + n) * 8) = p.u;
    } else {
        const int idx = (b - 784) * 256 + tid;    // 0 .. 110591
        const int e  = idx & 7;
        const int l  = (idx >> 3) & 63;
        const int ks = (idx >> 9) & 1;
        const int of = (idx >> 10) & 3;
        const int kv = idx >> 12;                 // 0..26
        const int o = of * 16 + (l & 15);
        const int c = ks * 32 + (l >> 4) * 8 + e;
        wt2[idx] = __float2half(w[(size_t)(o * 64 + c) * 27 + kv]);
    }
}

// Block = (tile, kz-plane): 3 waves (ky), 3 taps (kx) per wave.
// Fragment-direct: lane's sample registers ARE the MFMA B-fragment.
template <bool USE_PART>
__global__ __launch_bounds__(192, 8) void dconv_kernel(const float* __restrict__ offset,
                                                       const __half* __restrict__ xt,
                                                       const __half* __restrict__ wt2,
                                                       float* __restrict__ part,
                                                       float* __restrict__ out) {
    __shared__ float red_s[3][64][20];   // [ky-wave][o][n(+pad)] : 15.4 KB
    const int tid = threadIdx.x;
    const int lane = tid & 63;
    const int wv = tid >> 6;             // ky
    const int kz = blockIdx.x / NTILES_; // 0..2
    const int r  = blockIdx.x % NTILES_;
    // same-tile kz-blocks land on the same XCD; same-XCD blocks get consecutive tiles
    const int tile = (r & 7) * 196 + (r >> 3);
    const int n0 = tile * NT_;
    const int nl = lane & 15;
    const int n = n0 + nl;
    const int kv0 = kz * 9 + wv * 3;

    const int zo = n / HW_;
    const int rem = n - zo * HW_;
    const int yo = rem / W_;
    const int xo = rem - yo * W_;
    const __half* xg[2];
    const float* ob[2];
#pragma unroll
    for (int ph = 0; ph < 2; ++ph) {
        const int g = ph * 4 + (lane >> 4);
        xg[ph] = xt + (size_t)g * (N_ * 8);
        ob[ph] = offset + (size_t)g * (KV_ * 3 * N_) + n;
    }

    // all 3 taps' offsets loaded upfront (18 values), nontemporal
    float oz[3][2], oy[3][2], ox[3][2];
#pragma unroll
    for (int t = 0; t < 3; ++t)
#pragma unroll
        for (int ph = 0; ph < 2; ++ph) {
            const float* p = ob[ph] + (size_t)(kv0 + t) * 3 * N_;
            oz[t][ph] = __builtin_nontemporal_load(p);
            oy[t][ph] = __builtin_nontemporal_load(p + N_);
            ox[t][ph] = __builtin_nontemporal_load(p + 2 * N_);
        }

    f32x4 acc[4] = {};
    const int ky = wv;

#pragma unroll
    for (int kvi = 0; kvi < 3; ++kvi) {
        const int kv = kv0 + kvi;
        const int kx = kvi;

        // ---- sampling: build the two B-fragments in registers ----
        f16x8 bf[2];
#pragma unroll
        for (int ph = 0; ph < 2; ++ph) {
            float zc = (float)(zo + kz - 1) + oz[kvi][ph];
            float yc = (float)(yo + ky - 1) + oy[kvi][ph];
            float xc = (float)(xo + kx - 1) + ox[kvi][ph];
            float zf = floorf(zc), yf = floorf(yc), xf = floorf(xc);
            float dz = zc - zf, dy = yc - yf, dx = xc - xf;
            int z0 = (int)zf, y0 = (int)yf, x0 = (int)xf;
            int z1 = z0 + 1, y1 = y0 + 1, x1 = x0 + 1;
            float wz0 = (1.f - dz) * ((unsigned)z0 < (unsigned)D_ ? 1.f : 0.f);
            float wz1 = dz * ((unsigned)z1 < (unsigned)D_ ? 1.f : 0.f);
            float wy0 = (1.f - dy) * ((unsigned)y0 < (unsigned)H_ ? 1.f : 0.f);
            float wy1 = dy * ((unsigned)y1 < (unsigned)H_ ? 1.f : 0.f);
            float wx0 = (1.f - dx) * ((unsigned)x0 < (unsigned)W_ ? 1.f : 0.f);
            float wx1 = dx * ((unsigned)x1 < (unsigned)W_ ? 1.f : 0.f);
            int z0c = min(max(z0, 0), D_ - 1), z1c = min(max(z1, 0), D_ - 1);
            int y0c = min(max(y0, 0), H_ - 1), y1c = min(max(y1, 0), H_ - 1);
            int x0c = min(max(x0, 0), W_ - 1), x1c = min(max(x1, 0), W_ - 1);
            const uint4* xp = (const uint4*)xg[ph];
            int zy00 = z0c * HW_ + y0c * W_, zy01 = z0c * HW_ + y1c * W_;
            int zy10 = z1c * HW_ + y0c * W_, zy11 = z1c * HW_ + y1c * W_;
            // two independent hfma chains (depth 4 each) instead of one depth-8
            U4H a0, a1;
            a0.u = make_uint4(0u, 0u, 0u, 0u);
            a1.u = make_uint4(0u, 0u, 0u, 0u);
#define CORNER(ZY, XC, WF, A) do { \
                U4H d_; d_.u = xp[(ZY) + (XC)]; \
                __half2 w2_ = __float2half2_rn(WF); \
                A.h[0] = __hfma2(d_.h[0], w2_, A.h[0]); \
                A.h[1] = __hfma2(d_.h[1], w2_, A.h[1]); \
                A.h[2] = __hfma2(d_.h[2], w2_, A.h[2]); \
                A.h[3] = __hfma2(d_.h[3], w2_, A.h[3]); \
            } while (0)
            CORNER(zy00, x0c, wz0 * wy0 * wx0, a0);
            CORNER(zy00, x1c, wz0 * wy0 * wx1, a1);
            CORNER(zy01, x0c, wz0 * wy1 * wx0, a0);
            CORNER(zy01, x1c, wz0 * wy1 * wx1, a1);
            CORNER(zy10, x0c, wz1 * wy0 * wx0, a0);
            CORNER(zy10, x1c, wz1 * wy0 * wx1, a1);
            CORNER(zy11, x0c, wz1 * wy1 * wx0, a0);
            CORNER(zy11, x1c, wz1 * wy1 * wx1, a1);
#undef CORNER
            a0.h[0] = __hadd2(a0.h[0], a1.h[0]);
            a0.h[1] = __hadd2(a0.h[1], a1.h[1]);
            a0.h[2] = __hadd2(a0.h[2], a1.h[2]);
            a0.h[3] = __hadd2(a0.h[3], a1.h[3]);
            bf[ph] = a0.v;
        }

        // ---- 8 MFMA: C[o][n] += w[o][c] * val[c][n], K=64 ----
        const __half* wb = wt2 + (size_t)kv * 4096 + lane * 8;
#pragma unroll
        for (int of = 0; of < 4; ++of) {
            f16x8 a0 = *(const f16x8*)(wb + of * 1024);
            f16x8 a1 = *(const f16x8*)(wb + of * 1024 + 512);
            acc[of] = __builtin_amdgcn_mfma_f32_16x16x32_f16(a0, bf[0], acc[of], 0, 0, 0);
            acc[of] = __builtin_amdgcn_mfma_f32_16x16x32_f16(a1, bf[1], acc[of], 0, 0, 0);
        }
    }

    // ---- combine the 3 ky-waves' C tiles ----
#pragma unroll
    for (int of = 0; of < 4; ++of)
#pragma unroll
        for (int rr = 0; rr < 4; ++rr)
            red_s[wv][of * 16 + (lane >> 4) * 4 + rr][nl] = acc[of][rr];
    __syncthreads();
    for (int e = tid; e < 256; e += 192) {
        const int o = e >> 2, n4 = (e & 3) * 4;
        f32x4 s = *(const f32x4*)&red_s[0][o][n4]
                + *(const f32x4*)&red_s[1][o][n4]
                + *(const f32x4*)&red_s[2][o][n4];
        if (USE_PART) {
            *(f32x4*)(part + ((size_t)(kz * 64 + o)) * N_ + n0 + n4) = s;
        } else {
            float* dst = out + (size_t)o * N_ + n0 + n4;
            atomicAdd(dst + 0, s[0]);
            atomicAdd(dst + 1, s[1]);
            atomicAdd(dst + 2, s[2]);
            atomicAdd(dst + 3, s[3]);
        }
    }
}

// out = part[kz=0] + part[kz=1] + part[kz=2]
__global__ __launch_bounds__(256) void reduce_kernel(const float* __restrict__ part,
                                                     float* __restrict__ out) {
    const size_t flat = ((size_t)blockIdx.x * 256 + threadIdx.x) * 4;
    f32x4 s = *(const f32x4*)(part + flat)
            + *(const f32x4*)(part + (size_t)64 * N_ + flat)
            + *(const f32x4*)(part + (size_t)128 * N_ + flat);
    *(f32x4*)(out + flat) = s;
}

extern "C" void kernel_launch(void* const* d_in, const int* in_sizes, int n_in,
                              void* d_out, int out_size, void* d_ws, size_t ws_size,
                              hipStream_t stream) {
    const float* x      = (const float*)d_in[0];
    const float* offset = (const float*)d_in[1];
    const float* weight = (const float*)d_in[2];
    float* out = (float*)d_out;

    __half* xt  = (__half*)d_ws;                 // 3,211,264 B
    __half* wt2 = xt + (size_t)8 * N_ * 8;       // 221,184 B
    float* part = (float*)((char*)d_ws + 3432448);
    const size_t need = 3432448 + (size_t)3 * 64 * N_ * 4;  // ~22.7 MB

    prep_kernel<<<784 + 432, 256, 0, stream>>>(x, weight, xt, wt2);
    if (ws_size >= need) {
        dconv_kernel<true><<<3 * NTILES_, 192, 0, stream>>>(offset, xt, wt2, part, out);
        reduce_kernel<<<(64 * N_ / 4) / 256, 256, 0, stream>>>(part, out);
    } else {
        hipMemsetAsync(out, 0, (size_t)64 * N_ * sizeof(float), stream);
        dconv_kernel<false><<<3 * NTILES_, 192, 0, stream>>>(offset, xt, wt2, part, out);
    }
}

// Round 7
// 215.739 us; speedup vs baseline: 1.3807x; 1.3807x over previous
//
#include <hip/hip_runtime.h>
#include <hip/hip_fp16.h>

// Problem constants: x (1,64,8,56,56), offset (1,648,8,56,56),
// weight (64,64,3,3,3), stride=1, pad=1, cpg=8.
namespace {
constexpr int D_ = 8, H_ = 56, W_ = 56;
constexpr int HW_ = H_ * W_;
constexpr int KV_ = 27;
constexpr int N_ = D_ * H_ * W_;    // 25088
constexpr int NT_ = 16;             // n-cols per tile (one MFMA n-dim)
constexpr int NTILES_ = N_ / NT_;   // 1568 = 8 * 196
}

typedef _Float16 f16x8 __attribute__((ext_vector_type(8)));
typedef float f32x4 __attribute__((ext_vector_type(4)));

union U4H { uint4 u; __half2 h[4]; f16x8 v; };

// prep: xt[g][n][8] f16  and  wt2[kv][of][ks][lane][8] f16
//   wt2[kv][of][ks][l][e] = w[o = of*16 + (l&15)][c = ks*32 + (l>>4)*8 + e]
__global__ __launch_bounds__(256) void prep_kernel(const float* __restrict__ x,
                                                   const float* __restrict__ w,
                                                   __half* __restrict__ xt,
                                                   __half* __restrict__ wt2) {
    const int b = blockIdx.x, tid = threadIdx.x;
    if (b < 784) {
        const int g = b / 98;
        const int n = (b % 98) * 256 + tid;
        U4H p;
#pragma unroll
        for (int cc = 0; cc < 4; ++cc) {
            float lo = x[(size_t)(g * 8 + 2 * cc) * N_ + n];
            float hi = x[(size_t)(g * 8 + 2 * cc + 1) * N_ + n];
            p.h[cc] = __floats2half2_rn(lo, hi);
        }
        *(uint4*)(xt + ((size_t)g * N_ + n) * 8) = p.u;
    } else {
        const int idx = (b - 784) * 256 + tid;    // 0 .. 110591
        const int e  = idx & 7;
        const int l  = (idx >> 3) & 63;
        const int ks = (idx >> 9) & 1;
        const int of = (idx >> 10) & 3;
        const int kv = idx >> 12;                 // 0..26
        const int o = of * 16 + (l & 15);
        const int c = ks * 32 + (l >> 4) * 8 + e;
        wt2[idx] = __float2half(w[(size_t)(o * 64 + c) * 27 + kv]);
    }
}

// Issue one (tap, phase)'s 8 corner gathers into BUF; keep 6 interp weights in WW.
#define ISSUE(PH, KY, KX, OZ, OY, OX, BUF, WW) do {                            \
    float zc = (float)(zo + kz - 1) + (OZ);                                    \
    float yc = (float)(yo + (KY) - 1) + (OY);                                  \
    float xc = (float)(xo + (KX) - 1) + (OX);                                  \
    float zf = floorf(zc), yf = floorf(yc), xf = floorf(xc);                   \
    float dz = zc - zf, dy = yc - yf, dx = xc - xf;                            \
    int z0 = (int)zf, y0 = (int)yf, x0 = (int)xf;                              \
    int z1 = z0 + 1, y1 = y0 + 1, x1 = x0 + 1;                                 \
    WW[0] = (1.f - dz) * ((unsigned)z0 < (unsigned)D_ ? 1.f : 0.f);            \
    WW[1] = dz * ((unsigned)z1 < (unsigned)D_ ? 1.f : 0.f);                    \
    WW[2] = (1.f - dy) * ((unsigned)y0 < (unsigned)H_ ? 1.f : 0.f);            \
    WW[3] = dy * ((unsigned)y1 < (unsigned)H_ ? 1.f : 0.f);                    \
    WW[4] = (1.f - dx) * ((unsigned)x0 < (unsigned)W_ ? 1.f : 0.f);            \
    WW[5] = dx * ((unsigned)x1 < (unsigned)W_ ? 1.f : 0.f);                    \
    int z0c = min(max(z0, 0), D_ - 1), z1c = min(max(z1, 0), D_ - 1);          \
    int y0c = min(max(y0, 0), H_ - 1), y1c = min(max(y1, 0), H_ - 1);          \
    int x0c = min(max(x0, 0), W_ - 1), x1c = min(max(x1, 0), W_ - 1);          \
    const uint4* xp_ = xg[PH];                                                 \
    int zy00 = z0c * HW_ + y0c * W_, zy01 = z0c * HW_ + y1c * W_;              \
    int zy10 = z1c * HW_ + y0c * W_, zy11 = z1c * HW_ + y1c * W_;              \
    BUF[0] = xp_[zy00 + x0c]; BUF[1] = xp_[zy00 + x1c];                        \
    BUF[2] = xp_[zy01 + x0c]; BUF[3] = xp_[zy01 + x1c];                        \
    BUF[4] = xp_[zy10 + x0c]; BUF[5] = xp_[zy10 + x1c];                        \
    BUF[6] = xp_[zy11 + x0c]; BUF[7] = xp_[zy11 + x1c];                        \
} while (0)

#define CORN(DU, WF, A) do {                                                   \
    U4H d_; d_.u = (DU);                                                       \
    __half2 w2_ = __float2half2_rn(WF);                                        \
    A.h[0] = __hfma2(d_.h[0], w2_, A.h[0]);                                    \
    A.h[1] = __hfma2(d_.h[1], w2_, A.h[1]);                                    \
    A.h[2] = __hfma2(d_.h[2], w2_, A.h[2]);                                    \
    A.h[3] = __hfma2(d_.h[3], w2_, A.h[3]);                                    \
} while (0)

// Combine 8 buffered corners with stored interp weights -> one B-fragment.
#define CONSUME(BUF, WW, BF) do {                                              \
    U4H a0_, a1_;                                                              \
    a0_.u = make_uint4(0u, 0u, 0u, 0u);                                        \
    a1_.u = make_uint4(0u, 0u, 0u, 0u);                                        \
    float wzy00 = WW[0] * WW[2], wzy01 = WW[0] * WW[3];                        \
    float wzy10 = WW[1] * WW[2], wzy11 = WW[1] * WW[3];                        \
    CORN(BUF[0], wzy00 * WW[4], a0_); CORN(BUF[1], wzy00 * WW[5], a1_);        \
    CORN(BUF[2], wzy01 * WW[4], a0_); CORN(BUF[3], wzy01 * WW[5], a1_);        \
    CORN(BUF[4], wzy10 * WW[4], a0_); CORN(BUF[5], wzy10 * WW[5], a1_);        \
    CORN(BUF[6], wzy11 * WW[4], a0_); CORN(BUF[7], wzy11 * WW[5], a1_);        \
    a0_.h[0] = __hadd2(a0_.h[0], a1_.h[0]);                                    \
    a0_.h[1] = __hadd2(a0_.h[1], a1_.h[1]);                                    \
    a0_.h[2] = __hadd2(a0_.h[2], a1_.h[2]);                                    \
    a0_.h[3] = __hadd2(a0_.h[3], a1_.h[3]);                                    \
    BF = a0_.v;                                                                \
} while (0)

// Wave = (n-tile of 16, z-plane of 9 taps). Software-pipelined gather ring:
// bufA/bufB hold the in-flight (tap,phase) gathers; next unit's loads are
// issued immediately after the current unit's registers are consumed.
__global__ __launch_bounds__(192, 3) void dconv_kernel(const float* __restrict__ offset,
                                                       const __half* __restrict__ xt,
                                                       const __half* __restrict__ wt2,
                                                       float* __restrict__ out) {
    __shared__ float red_s[3][64][20];   // [z-plane wave][o][n(+pad)]
    const int tid = threadIdx.x;
    const int lane = tid & 63;
    const int wv = tid >> 6;             // z-plane (kz == wv)
    const int r = blockIdx.x;
    const int tile = (r & 7) * 196 + (r >> 3);  // XCD gets a contiguous z-slice
    const int n0 = tile * NT_;
    const int nl = lane & 15;
    const int n = n0 + nl;
    const int kv0 = wv * 9;
    const int kz = wv;

    const int zo = n / HW_;
    const int rem = n - zo * HW_;
    const int yo = rem / W_;
    const int xo = rem - yo * W_;
    const uint4* xg[2];
    const float* ob[2];
#pragma unroll
    for (int ph = 0; ph < 2; ++ph) {
        const int g = ph * 4 + (lane >> 4);
        xg[ph] = (const uint4*)(xt + (size_t)g * (N_ * 8));
        ob[ph] = offset + (size_t)g * (KV_ * 3 * N_) + n;
    }

    uint4 bufA[8], bufB[8];
    float wA[6], wB[6];
    f32x4 acc[4] = {};
    f16x8 bf0, bf1;

    // ---- prologue: tap-0 offsets -> issue both phase-units; tap-1 offsets ----
    float o0z[2], o0y[2], o0x[2], onz[2], ony[2], onx[2];
#pragma unroll
    for (int ph = 0; ph < 2; ++ph) {
        const float* p = ob[ph] + (size_t)kv0 * 3 * N_;
        o0z[ph] = __builtin_nontemporal_load(p);
        o0y[ph] = __builtin_nontemporal_load(p + N_);
        o0x[ph] = __builtin_nontemporal_load(p + 2 * N_);
    }
    ISSUE(0, 0, 0, o0z[0], o0y[0], o0x[0], bufA, wA);
    ISSUE(1, 0, 0, o0z[1], o0y[1], o0x[1], bufB, wB);
#pragma unroll
    for (int ph = 0; ph < 2; ++ph) {
        const float* p = ob[ph] + (size_t)(kv0 + 1) * 3 * N_;
        onz[ph] = __builtin_nontemporal_load(p);
        ony[ph] = __builtin_nontemporal_load(p + N_);
        onx[ph] = __builtin_nontemporal_load(p + 2 * N_);
    }

#pragma unroll
    for (int t = 0; t < 9; ++t) {
        const int kv = kv0 + t;
        const __half* wb = wt2 + (size_t)kv * 4096 + lane * 8;

        // A-fragments ks=0 (of 0..3)
        f16x8 af00 = *(const f16x8*)(wb);
        f16x8 af01 = *(const f16x8*)(wb + 1024);
        f16x8 af02 = *(const f16x8*)(wb + 2048);
        f16x8 af03 = *(const f16x8*)(wb + 3072);

        CONSUME(bufA, wA, bf0);
        if (t < 8)
            ISSUE(0, (t + 1) / 3, (t + 1) % 3, onz[0], ony[0], onx[0], bufA, wA);

        __builtin_amdgcn_s_setprio(1);
        acc[0] = __builtin_amdgcn_mfma_f32_16x16x32_f16(af00, bf0, acc[0], 0, 0, 0);
        acc[1] = __builtin_amdgcn_mfma_f32_16x16x32_f16(af01, bf0, acc[1], 0, 0, 0);
        acc[2] = __builtin_amdgcn_mfma_f32_16x16x32_f16(af02, bf0, acc[2], 0, 0, 0);
        acc[3] = __builtin_amdgcn_mfma_f32_16x16x32_f16(af03, bf0, acc[3], 0, 0, 0);
        __builtin_amdgcn_s_setprio(0);

        // A-fragments ks=1
        f16x8 af10 = *(const f16x8*)(wb + 512);
        f16x8 af11 = *(const f16x8*)(wb + 1536);
        f16x8 af12 = *(const f16x8*)(wb + 2560);
        f16x8 af13 = *(const f16x8*)(wb + 3584);

        CONSUME(bufB, wB, bf1);
        if (t < 8)
            ISSUE(1, (t + 1) / 3, (t + 1) % 3, onz[1], ony[1], onx[1], bufB, wB);

        // offsets two taps ahead
        float tnz[2], tny[2], tnx[2];
        if (t < 7) {
#pragma unroll
            for (int ph = 0; ph < 2; ++ph) {
                const float* p = ob[ph] + (size_t)(kv + 2) * 3 * N_;
                tnz[ph] = __builtin_nontemporal_load(p);
                tny[ph] = __builtin_nontemporal_load(p + N_);
                tnx[ph] = __builtin_nontemporal_load(p + 2 * N_);
            }
        }

        __builtin_amdgcn_s_setprio(1);
        acc[0] = __builtin_amdgcn_mfma_f32_16x16x32_f16(af10, bf1, acc[0], 0, 0, 0);
        acc[1] = __builtin_amdgcn_mfma_f32_16x16x32_f16(af11, bf1, acc[1], 0, 0, 0);
        acc[2] = __builtin_amdgcn_mfma_f32_16x16x32_f16(af12, bf1, acc[2], 0, 0, 0);
        acc[3] = __builtin_amdgcn_mfma_f32_16x16x32_f16(af13, bf1, acc[3], 0, 0, 0);
        __builtin_amdgcn_s_setprio(0);

        if (t < 7) {
#pragma unroll
            for (int ph = 0; ph < 2; ++ph) {
                onz[ph] = tnz[ph]; ony[ph] = tny[ph]; onx[ph] = tnx[ph];
            }
        }
    }

    // ---- combine the 3 z-plane waves' C tiles ----
#pragma unroll
    for (int of = 0; of < 4; ++of)
#pragma unroll
        for (int rr = 0; rr < 4; ++rr)
            red_s[wv][of * 16 + (lane >> 4) * 4 + rr][nl] = acc[of][rr];
    __syncthreads();
    for (int e = tid; e < 256; e += 192) {
        const int o = e >> 2, n4 = (e & 3) * 4;
        f32x4 s = *(const f32x4*)&red_s[0][o][n4]
                + *(const f32x4*)&red_s[1][o][n4]
                + *(const f32x4*)&red_s[2][o][n4];
        *(f32x4*)(out + (size_t)o * N_ + n0 + n4) = s;
    }
}

extern "C" void kernel_launch(void* const* d_in, const int* in_sizes, int n_in,
                              void* d_out, int out_size, void* d_ws, size_t ws_size,
                              hipStream_t stream) {
    const float* x      = (const float*)d_in[0];
    const float* offset = (const float*)d_in[1];
    const float* weight = (const float*)d_in[2];
    float* out = (float*)d_out;

    __half* xt  = (__half*)d_ws;                 // 8*25088*8 halves = 3.2 MB
    __half* wt2 = xt + (size_t)8 * N_ * 8;       // 27*4096 halves = 216 KB

    prep_kernel<<<784 + 432, 256, 0, stream>>>(x, weight, xt, wt2);
    dconv_kernel<<<NTILES_, 192, 0, stream>>>(offset, xt, wt2, out);
}